// Round 10
// baseline (144.704 us; speedup 1.0000x reference)
//
#include <hip/hip_runtime.h>
#include <hip/hip_bf16.h>
#include <math.h>

// LargeMarginLoss: loss = log1p(neg_sum / pos_sum) over e = exp(30*(cos_sim - 0.2))
// B=8192, D=512, labels in [0,100). Output: 1 float32 scalar.
//
// norm (fp32 norms -> bf16 rows); fused 256^2 MFMA GEMM-loss with the m201
// software-pipelined phase schedule: per phase {stage 1 half-K unit (3 units
// ahead, counted vmcnt(8)); ds_read NEXT cluster's fragments; barrier;
// 32 MFMA on PREVIOUS phase's registers; barrier}. 2 phases per K-tile(64).

#define BDIM 8192
#define DDIM 512
#define MARGIN 0.2f
#define SCALE 30.0f

#define BT 256               // output tile (BM=BN)
#define BK 64                // K-tile (2 kk-halves of 32)
#define NKT (DDIM / BK)      // 8 K-tiles
#define NT (BDIM / BT)       // 32
#define NBLK (NT * (NT + 1) / 2)   // 528 upper-tri tiles (= 8 XCDs * 66)

typedef __hip_bfloat16 bf16;
using f32x4  = __attribute__((ext_vector_type(4))) float;
using bf16x8 = __attribute__((ext_vector_type(8))) short;
using us8    = __attribute__((ext_vector_type(8))) unsigned short;

#define GLOAD_LDS16(gp, lp)                                                    \
    __builtin_amdgcn_global_load_lds(                                          \
        (const __attribute__((address_space(1))) unsigned int*)(gp),           \
        (__attribute__((address_space(3))) unsigned int*)(lp), 16, 0, 0)

__device__ __forceinline__ unsigned short f2bf(float x) {
    union { bf16 h; unsigned short u; } c;
    c.h = __float2bfloat16(x);
    return c.u;
}

// ---------------------------------------------------------------------------
// Kernel 1: row L2-normalize (fp32 norms), emit bf16. One wave per row.
__global__ __launch_bounds__(256)
void norm_rows_kernel(const float* __restrict__ emb, bf16* __restrict__ nout,
                      double* __restrict__ accum, unsigned* __restrict__ ctr) {
    if (blockIdx.x == 0 && threadIdx.x == 0) {
        accum[0] = 0.0; accum[1] = 0.0; *ctr = 0u;
    }
    const int row  = blockIdx.x * 4 + (threadIdx.x >> 6);
    const int lane = threadIdx.x & 63;
    const float4* src = (const float4*)(emb + (size_t)row * DDIM) + lane * 2;
    const float4 a = src[0];
    const float4 b = src[1];
    float ss = a.x * a.x + a.y * a.y + a.z * a.z + a.w * a.w
             + b.x * b.x + b.y * b.y + b.z * b.z + b.w * b.w;
    #pragma unroll
    for (int off = 1; off < 64; off <<= 1) ss += __shfl_xor(ss, off, 64);
    const float inv = 1.0f / fmaxf(sqrtf(ss), 1e-8f);
    float v[8] = { a.x, a.y, a.z, a.w, b.x, b.y, b.z, b.w };
    us8 o;
    #pragma unroll
    for (int i = 0; i < 8; ++i) o[i] = f2bf(v[i] * inv);
    *((us8*)(nout + (size_t)row * DDIM) + lane) = o;
}

// ---------------------------------------------------------------------------
// Kernel 2: 256^2-tile fused GEMM-loss, software-pipelined phases.
//   8 waves (2M x 4N); per-wave 128x64 out = 8x4 frags of 16x16x32.
//   LDS: As/Bs[2 buf][2 kk][256*32] bf16 = 128 KB total.
//   S-unit S_kk(t) = A-half + B-half at (t,kk): 4 gload_lds/thread.
//   Swizzle per 32-col half (HW-verified 0 conflicts): physical chunk16 =
//   logical ^ ((row>>1)&3); pre-applied on global source, same XOR on read.
//   Phase A(t): stage S1(t+1); vmcnt(8); read U1(t); bar; 32 MFMA kk0(U0); bar
//   Phase B(t): stage S0(t+2); vmcnt(8); read U0(t+1); bar; 32 MFMA kk1(U1); bar
__global__ __launch_bounds__(512)
void gemm_loss_kernel(const bf16* __restrict__ nmat,
                      const int* __restrict__ labels,
                      double* __restrict__ accum, unsigned* __restrict__ ctr,
                      float* __restrict__ out) {
    // --- XCD-contiguous triangular decode ---
    const int hw = blockIdx.x;
    const int l = (hw & 7) * (NBLK / 8) + (hw >> 3);
    auto tri = [](int b) { return ((65 - b) * b) >> 1; };
    int bi = (int)((65.0 - sqrt(4225.0 - 8.0 * (double)l)) * 0.5);
    bi = bi < 0 ? 0 : (bi > 31 ? 31 : bi);
    while (bi > 0 && tri(bi) > l) --bi;
    while (tri(bi + 1) <= l) ++bi;
    const int bj = bi + (l - tri(bi));

    __shared__ alignas(16) short As[2][2][256 * 32];   // 64 KB
    __shared__ alignas(16) short Bs[2][2][256 * 32];   // 64 KB
    __shared__ int lr[BT], lc[BT];
    __shared__ double red[16];

    const int tix = threadIdx.x, wid = tix >> 6, lane = tix & 63;
    if (tix < 256) lr[tix] = labels[bi * BT + tix];
    else           lc[tix - 256] = labels[bj * BT + (tix - 256)];

    const int wm = wid >> 2;          // 0..1  (M half)
    const int wn = wid & 3;           // 0..3  (N quarter)

    // staging addresses: load q covers rows q*128 + wid*16 + (lane>>2),
    // col chunk lane&3 pre-swizzled: ^((row>>1)&3) = ^((lane>>3)&3).
    const int srow = wid * 16 + (lane >> 2);
    const int scol = ((lane & 3) ^ ((lane >> 3) & 3)) * 8;
    const bf16* gA = nmat + (size_t)(bi * BT + srow) * DDIM + scol;
    const bf16* gB = nmat + (size_t)(bj * BT + srow) * DDIM + scol;
    const int ldst = (wid * 16) * 32;  // wave-uniform dest within a half

    // S-unit: A-half + B-half at (kt, kk) into buf
    #define STG_S(buf, kt, kk)                                                 \
        do {                                                                   \
            GLOAD_LDS16(gA + (kt) * 64 + (kk) * 32, &As[buf][kk][ldst]);       \
            GLOAD_LDS16(gA + (size_t)128 * DDIM + (kt) * 64 + (kk) * 32,       \
                        &As[buf][kk][128 * 32 + ldst]);                        \
            GLOAD_LDS16(gB + (kt) * 64 + (kk) * 32, &Bs[buf][kk][ldst]);       \
            GLOAD_LDS16(gB + (size_t)128 * DDIM + (kt) * 64 + (kk) * 32,       \
                        &Bs[buf][kk][128 * 32 + ldst]);                        \
        } while (0)

    // fragment read: row*32 + swizzled chunk
    const int swzc = (((lane >> 4) ^ ((lane >> 1) & 3)) * 8);
    const int arw  = (lane & 15) * 32 + swzc;

    #define READ_U(buf, kk, ua, ub)                                            \
        do {                                                                   \
            _Pragma("unroll")                                                  \
            for (int m = 0; m < 8; ++m)                                        \
                ua[m] = *(const bf16x8*)&As[buf][kk][(wm * 128 + m * 16) * 32 + arw]; \
            _Pragma("unroll")                                                  \
            for (int n = 0; n < 4; ++n)                                        \
                ub[n] = *(const bf16x8*)&Bs[buf][kk][(wn * 64 + n * 16) * 32 + arw];  \
        } while (0)

    #define MFMA32(ua, ub)                                                     \
        do {                                                                   \
            __builtin_amdgcn_s_setprio(1);                                     \
            _Pragma("unroll")                                                  \
            for (int m = 0; m < 8; ++m)                                        \
                _Pragma("unroll")                                              \
                for (int n = 0; n < 4; ++n)                                    \
                    acc[m][n] = __builtin_amdgcn_mfma_f32_16x16x32_bf16(       \
                        ua[m], ub[n], acc[m][n], 0, 0, 0);                     \
            __builtin_amdgcn_s_setprio(0);                                     \
        } while (0)

    #define BAR()                                                              \
        do {                                                                   \
            asm volatile("" ::: "memory");                                     \
            __builtin_amdgcn_s_barrier();                                      \
            asm volatile("" ::: "memory");                                     \
        } while (0)

    f32x4 acc[8][4] = {};
    bf16x8 u0a[8], u0b[4], u1a[8], u1b[4];

    // --- prologue: stage S0(0), S1(0), S0(1); wait S0(0); read U0(0) ---
    STG_S(0, 0, 0);
    STG_S(0, 0, 1);
    STG_S(1, 1, 0);
    asm volatile("s_waitcnt vmcnt(8)" ::: "memory");
    __syncthreads();                     // also publishes lr/lc
    READ_U(0, 0, u0a, u0b);

    #pragma unroll
    for (int t = 0; t < NKT; ++t) {
        const int cur = t & 1, nxt = cur ^ 1;
        // ---- phase A: MFMA kk0 of tile t; read U1(t); stage S1(t+1) ----
        if (t + 1 < NKT) STG_S(nxt, t + 1, 1);
        if (t < NKT - 1) { asm volatile("s_waitcnt vmcnt(8)" ::: "memory"); }
        else             { asm volatile("s_waitcnt vmcnt(0)" ::: "memory"); }
        READ_U(cur, 1, u1a, u1b);
        BAR();
        MFMA32(u0a, u0b);                // kk0, regs read last phase
        BAR();
        // ---- phase B: MFMA kk1 of tile t; read U0(t+1); stage S0(t+2) ----
        if (t + 2 < NKT) STG_S(cur, t + 2, 0);
        if (t + 1 < NKT) {
            if (t + 2 < NKT) { asm volatile("s_waitcnt vmcnt(8)" ::: "memory"); }
            else             { asm volatile("s_waitcnt vmcnt(4)" ::: "memory"); }
            READ_U(nxt, 0, u0a, u0b);
        }
        BAR();
        MFMA32(u1a, u1b);                // kk1
        BAR();
    }
    #undef STG_S
    #undef READ_U
    #undef MFMA32
    #undef BAR

    // --- epilogue: e = exp(SCALE*(sim - MARGIN)); masked accumulate ---
    // C/D layout: col = lane&15, row = (lane>>4)*4 + reg.
    float posf = 0.0f, negf = 0.0f;
    const int rbase = wm * 128 + (lane >> 4) * 4;
    const int cbase = wn * 64 + (lane & 15);
    #pragma unroll
    for (int m = 0; m < 8; ++m) {
        #pragma unroll
        for (int n = 0; n < 4; ++n) {
            const int ljv = lc[cbase + n * 16];
            #pragma unroll
            for (int r = 0; r < 4; ++r) {
                const float e = __expf(fmaf(acc[m][n][r], SCALE, -SCALE * MARGIN));
                if (lr[rbase + m * 16 + r] == ljv) posf += e; else negf += e;
            }
        }
    }

    double dp = (double)posf, dn = (double)negf;
    #pragma unroll
    for (int o = 32; o > 0; o >>= 1) {
        dp += __shfl_down(dp, o, 64);
        dn += __shfl_down(dn, o, 64);
    }
    if (lane == 0) { red[wid * 2] = dp; red[wid * 2 + 1] = dn; }
    __syncthreads();
    if (tix == 0) {
        const double w = (bi == bj) ? 1.0 : 2.0;
        double p = 0.0, q = 0.0;
        #pragma unroll
        for (int i = 0; i < 8; ++i) { p += red[2 * i]; q += red[2 * i + 1]; }
        atomicAdd(&accum[0], p * w);
        atomicAdd(&accum[1], q * w);
        __threadfence();
        unsigned prev = atomicAdd(ctr, 1u);
        if (prev == NBLK - 1) {
            __threadfence();
            double pp = atomicAdd(&accum[0], 0.0);
            double qq = atomicAdd(&accum[1], 0.0);
            out[0] = (float)log1p(qq / pp);
        }
    }
}

// ---------------------------------------------------------------------------
extern "C" void kernel_launch(void* const* d_in, const int* in_sizes, int n_in,
                              void* d_out, int out_size, void* d_ws, size_t ws_size,
                              hipStream_t stream) {
    const float* emb  = (const float*)d_in[0];
    const int* labels = (const int*)d_in[1];
    float* out        = (float*)d_out;

    double* accum = (double*)d_ws;                       // 2 doubles
    unsigned* ctr = (unsigned*)((char*)d_ws + 16);
    bf16* nmat    = (bf16*)((char*)d_ws + 256);          // 8 MB

    norm_rows_kernel<<<BDIM / 4, 256, 0, stream>>>(emb, nmat, accum, ctr);
    gemm_loss_kernel<<<NBLK, 512, 0, stream>>>(nmat, labels, accum, ctr, out);
}